// Round 1
// baseline (593.024 us; speedup 1.0000x reference)
//
#include <hip/hip_runtime.h>
#include <cstdint>

// Problem constants (fixed by the reference file).
#define Bn 64
#define Cn 256
#define Hn 56
#define Wn 56
#define HM 52            // H - (BS-1)
#define WM 52
#define BS 5
#define NPLANES (Bn * Cn)          // 16384
#define PLANE (Hn * Wn)            // 3136
#define COUNTM ((long long)NPLANES * PLANE)  // 51380224

// ---------------------------------------------------------------------------
// Pass 1: one block per (b,c) plane. Build 52-bit row masks via __ballot,
// dilate horizontally with shift-ORs, vertically with a <=5-row OR window,
// write 56 packed uint64 rows per plane, and atomicAdd the dilated popcount.
// ---------------------------------------------------------------------------
__global__ __launch_bounds__(256) void dilate_count_kernel(
    const int* __restrict__ mask,
    uint64_t* __restrict__ dil,
    unsigned long long* __restrict__ counter)
{
    __shared__ uint64_t hdil[HM];
    __shared__ int scnt;

    const int plane = blockIdx.x;
    const int tid   = threadIdx.x;
    const int wave  = tid >> 6;     // 4 waves of 64
    const int lane  = tid & 63;

    if (tid == 0) scnt = 0;

    const int* mbase = mask + (size_t)plane * (HM * WM);

    // 4 waves x 13 rows each = 52 rows. One coalesced 52-lane load per row,
    // one ballot -> the whole row bitmask.
    #pragma unroll
    for (int r = 0; r < 13; ++r) {
        const int row = wave * 13 + r;
        const int v = (lane < WM) ? mbase[row * WM + lane] : 0;
        uint64_t bal = __ballot(v != 0);
        bal &= (1ull << WM) - 1ull;
        // horizontal dilation: bit j = OR of mask bits [j-4, j]  (bits 0..55)
        const uint64_t hd = bal | (bal << 1) | (bal << 2) | (bal << 3) | (bal << 4);
        if (lane == 0) hdil[row] = hd;
    }
    __syncthreads();

    if (tid < Hn) {
        // vertical dilation: output row o = OR of hdil rows [o-4, o] clamped to [0,51]
        int lo = tid - (BS - 1); if (lo < 0) lo = 0;
        int hi = tid;            if (hi > HM - 1) hi = HM - 1;
        uint64_t acc = 0;
        for (int r = lo; r <= hi; ++r) acc |= hdil[r];
        dil[(size_t)plane * Hn + tid] = acc;
        atomicAdd(&scnt, __popcll(acc));   // LDS atomic
    }
    __syncthreads();
    if (tid == 0) atomicAdd(counter, (unsigned long long)scnt);  // one global atomic/block
}

// ---------------------------------------------------------------------------
// Pass 2: float4 streaming apply. 12,845,056 float4s = 50176 blocks x 256
// threads exactly (no bounds check). Each thread pulls 4 bits from the packed
// dilated row and writes x * scale or 0.
// ---------------------------------------------------------------------------
__global__ __launch_bounds__(256) void apply_kernel(
    const float4* __restrict__ x4,
    const uint64_t* __restrict__ dil,
    const unsigned long long* __restrict__ counter,
    float4* __restrict__ out4)
{
    const int i = blockIdx.x * 256 + threadIdx.x;

    // scale = countM / count_ones ; integer count is exact.
    const long long ones = COUNTM - (long long)(*counter);
    const float scale = (float)COUNTM / (float)ones;

    const int idx   = i << 2;                 // element index, multiple of 4
    const int plane = idx / PLANE;            // const-div -> mulhi
    const int rem   = idx - plane * PLANE;
    const int h     = rem / Wn;
    const int w0    = rem - h * Wn;           // in {0,4,...,52}

    const uint64_t row = dil[plane * Hn + h];
    const unsigned bits = (unsigned)(row >> w0) & 0xFu;

    const float4 v = x4[i];
    float4 o;
    o.x = (bits & 1u) ? 0.0f : v.x * scale;
    o.y = (bits & 2u) ? 0.0f : v.y * scale;
    o.z = (bits & 4u) ? 0.0f : v.z * scale;
    o.w = (bits & 8u) ? 0.0f : v.w * scale;
    out4[i] = o;
}

extern "C" void kernel_launch(void* const* d_in, const int* in_sizes, int n_in,
                              void* d_out, int out_size, void* d_ws, size_t ws_size,
                              hipStream_t stream)
{
    const float* x    = (const float*)d_in[0];
    const int*   mask = (const int*)d_in[1];
    // d_in[2] = block_size (scalar 5) — fixed by the reference, hardcoded.

    unsigned long long* counter = (unsigned long long*)d_ws;
    uint64_t* dil = (uint64_t*)((char*)d_ws + 16);   // 16384*56*8 = 7,340,032 B

    // ws is re-poisoned to 0xAA before every call — zero the counter.
    hipMemsetAsync(d_ws, 0, 16, stream);

    dilate_count_kernel<<<NPLANES, 256, 0, stream>>>(mask, dil, counter);

    const int n4 = (int)(COUNTM / 4);                // 12,845,056 = 50176 * 256
    apply_kernel<<<n4 / 256, 256, 0, stream>>>(
        (const float4*)x, dil, counter, (float4*)d_out);
}

// Round 2
// 579.990 us; speedup vs baseline: 1.0225x; 1.0225x over previous
//
#include <hip/hip_runtime.h>
#include <cstdint>

// Problem constants (fixed by the reference file).
#define Bn 64
#define Cn 256
#define Hn 56
#define Wn 56
#define HM 52            // H - (BS-1)
#define WM 52
#define BS 5
#define NPLANES (Bn * Cn)          // 16384
#define PLANE (Hn * Wn)            // 3136
#define ROW_I4 13                  // 52 ints = 13 int4 per mask row
#define PLANE_I4 (HM * ROW_I4)     // 676 int4 per mask plane
#define COUNTM ((long long)NPLANES * PLANE)  // 51380224

// ---------------------------------------------------------------------------
// Pass 1: one block per (b,c) plane. Stream the mask as int4 (16 B/lane,
// fully coalesced, 3 independent loads/thread), collapse each int4 to a
// 4-bit nibble, OR nibbles into per-row LDS bitmasks. Wave 0 then does the
// vertical OR window + horizontal shift-OR dilation (they commute), writes
// 56 packed uint64 rows, and shuffle-reduces the popcount to one global
// atomicAdd per block.
// ---------------------------------------------------------------------------
__global__ __launch_bounds__(256) void dilate_count_kernel(
    const int4* __restrict__ mask4,
    uint64_t* __restrict__ dil,
    unsigned long long* __restrict__ counter)
{
    __shared__ unsigned long long hrow[HM];

    const int plane = blockIdx.x;
    const int tid   = threadIdx.x;

    if (tid < HM) hrow[tid] = 0ull;
    __syncthreads();

    const int4* mbase = mask4 + (size_t)plane * PLANE_I4;

    // 676 = 2*256 + 164 : threads issue 2-3 independent 16B loads.
    #pragma unroll
    for (int k = 0; k < 3; ++k) {
        const int i = tid + k * 256;
        if (i < PLANE_I4) {
            const int4 m = mbase[i];
            const unsigned nib = (m.x != 0 ? 1u : 0u) | (m.y != 0 ? 2u : 0u) |
                                 (m.z != 0 ? 4u : 0u) | (m.w != 0 ? 8u : 0u);
            if (nib) {                      // ~92% skipped at gamma=0.02
                const int row = i / ROW_I4;
                const int c4  = (i - row * ROW_I4) * 4;
                atomicOr(&hrow[row], (unsigned long long)nib << c4);
            }
        }
    }
    __syncthreads();

    // Wave 0 finishes the plane.
    if (tid < 64) {
        unsigned long long acc = 0ull;
        if (tid < Hn) {
            // vertical OR window over raw rows [tid-4, tid] clamped to [0,51]
            int lo = tid - (BS - 1); if (lo < 0) lo = 0;
            int hi = tid;            if (hi > HM - 1) hi = HM - 1;
            for (int r = lo; r <= hi; ++r) acc |= hrow[r];
            // horizontal dilation (commutes with vertical OR); bits land in 0..55
            acc = acc | (acc << 1) | (acc << 2) | (acc << 3) | (acc << 4);
            dil[(size_t)plane * Hn + tid] = acc;
        }
        int pc = (tid < Hn) ? __popcll(acc) : 0;
        #pragma unroll
        for (int off = 32; off > 0; off >>= 1)
            pc += __shfl_down(pc, off, 64);
        if (tid == 0) atomicAdd(counter, (unsigned long long)pc);
    }
}

// ---------------------------------------------------------------------------
// Pass 2: float4 streaming apply. 12,845,056 float4s = 50176 blocks x 256
// threads exactly (no bounds check). Each thread pulls 4 bits from the packed
// dilated row and writes x * scale or 0.
// ---------------------------------------------------------------------------
__global__ __launch_bounds__(256) void apply_kernel(
    const float4* __restrict__ x4,
    const uint64_t* __restrict__ dil,
    const unsigned long long* __restrict__ counter,
    float4* __restrict__ out4)
{
    const int i = blockIdx.x * 256 + threadIdx.x;   // float4 index

    // scale = countM / count_ones ; integer count is exact.
    const long long ones = COUNTM - (long long)(*counter);
    const float scale = (float)COUNTM / (float)ones;

    const int plane = i / (PLANE / 4);              // 784 float4 per plane
    const int r4    = i - plane * (PLANE / 4);
    const int h     = r4 / (Wn / 4);                // 14 float4 per row
    const int w0    = (r4 - h * (Wn / 4)) * 4;      // in {0,4,...,52}

    const uint64_t row = dil[plane * Hn + h];
    const unsigned bits = (unsigned)(row >> w0) & 0xFu;

    const float4 v = x4[i];
    float4 o;
    o.x = (bits & 1u) ? 0.0f : v.x * scale;
    o.y = (bits & 2u) ? 0.0f : v.y * scale;
    o.z = (bits & 4u) ? 0.0f : v.z * scale;
    o.w = (bits & 8u) ? 0.0f : v.w * scale;
    out4[i] = o;
}

extern "C" void kernel_launch(void* const* d_in, const int* in_sizes, int n_in,
                              void* d_out, int out_size, void* d_ws, size_t ws_size,
                              hipStream_t stream)
{
    const float* x    = (const float*)d_in[0];
    const int*   mask = (const int*)d_in[1];
    // d_in[2] = block_size (scalar 5) — fixed by the reference, hardcoded.

    unsigned long long* counter = (unsigned long long*)d_ws;
    uint64_t* dil = (uint64_t*)((char*)d_ws + 16);   // 16384*56*8 = 7,340,032 B

    // ws is re-poisoned to 0xAA before every call — zero the counter.
    hipMemsetAsync(d_ws, 0, 16, stream);

    dilate_count_kernel<<<NPLANES, 256, 0, stream>>>(
        (const int4*)mask, dil, counter);

    const int n4 = (int)(COUNTM / 4);                // 12,845,056 = 50176 * 256
    apply_kernel<<<n4 / 256, 256, 0, stream>>>(
        (const float4*)x, dil, counter, (float4*)d_out);
}

// Round 3
// 446.309 us; speedup vs baseline: 1.3287x; 1.2995x over previous
//
#include <hip/hip_runtime.h>
#include <cstdint>

// Problem constants (fixed by the reference file).
#define Bn 64
#define Cn 256
#define Hn 56
#define Wn 56
#define HM 52            // H - (BS-1)
#define WM 52
#define BS 5
#define NPLANES (Bn * Cn)          // 16384
#define PLANE (Hn * Wn)            // 3136
#define ROW_I4 13                  // 52 ints = 13 int4 per mask row
#define PLANE_I4 (HM * ROW_I4)     // 676 int4 per mask plane
#define DIL_WORDS (NPLANES * Hn)   // 917504 packed uint64 rows
#define COUNTM ((long long)NPLANES * PLANE)  // 51380224

// ---------------------------------------------------------------------------
// Pass 1: one block per (b,c) plane. Pure streaming — NO global atomics
// (R2 post-mortem: 16384 same-address atomicAdds serialized the whole grid
// at ~13 ns each ≈ the entire 209 µs). Load mask as int4 (16 B/lane), build
// per-row bitmasks via sparse LDS atomicOr, vertical OR window + horizontal
// shift-OR (they commute), write 56 packed uint64 rows, retire immediately.
// ---------------------------------------------------------------------------
__global__ __launch_bounds__(256) void dilate_kernel(
    const int4* __restrict__ mask4,
    uint64_t* __restrict__ dil)
{
    __shared__ unsigned long long hrow[HM];

    const int plane = blockIdx.x;
    const int tid   = threadIdx.x;

    if (tid < HM) hrow[tid] = 0ull;
    __syncthreads();

    const int4* mbase = mask4 + (size_t)plane * PLANE_I4;

    // 676 = 2*256 + 164 : threads issue 2-3 independent 16B loads.
    #pragma unroll
    for (int k = 0; k < 3; ++k) {
        const int i = tid + k * 256;
        if (i < PLANE_I4) {
            const int4 m = mbase[i];
            const unsigned nib = (m.x != 0 ? 1u : 0u) | (m.y != 0 ? 2u : 0u) |
                                 (m.z != 0 ? 4u : 0u) | (m.w != 0 ? 8u : 0u);
            if (nib) {                      // ~92% skipped at gamma=0.02
                const int row = i / ROW_I4;
                const int c4  = (i - row * ROW_I4) * 4;
                atomicOr(&hrow[row], (unsigned long long)nib << c4);
            }
        }
    }
    __syncthreads();

    if (tid < Hn) {
        // vertical OR window over raw rows [tid-4, tid] clamped to [0,51]
        int lo = tid - (BS - 1); if (lo < 0) lo = 0;
        int hi = tid;            if (hi > HM - 1) hi = HM - 1;
        unsigned long long acc = 0ull;
        for (int r = lo; r <= hi; ++r) acc |= hrow[r];
        // horizontal dilation (commutes with vertical OR); bits land in 0..55
        acc = acc | (acc << 1) | (acc << 2) | (acc << 3) | (acc << 4);
        dil[(size_t)plane * Hn + tid] = acc;
    }
}

// ---------------------------------------------------------------------------
// Pass 1.5: popcount the 7.3 MB packed dil array. 256 blocks x 256 threads,
// coalesced grid-stride (14 iters), wave shuffle-reduce + LDS, 256 total
// global atomics (vs 16384 before).
// ---------------------------------------------------------------------------
__global__ __launch_bounds__(256) void count_kernel(
    const uint64_t* __restrict__ dil,
    unsigned long long* __restrict__ counter)
{
    __shared__ int wsum[4];
    const int gtid = blockIdx.x * 256 + threadIdx.x;   // 65536 threads

    int pc = 0;
    #pragma unroll
    for (int k = 0; k < 14; ++k)                       // 65536*14 = 917504
        pc += __popcll(dil[gtid + k * 65536]);

    #pragma unroll
    for (int off = 32; off > 0; off >>= 1)
        pc += __shfl_down(pc, off, 64);
    if ((threadIdx.x & 63) == 0) wsum[threadIdx.x >> 6] = pc;
    __syncthreads();
    if (threadIdx.x == 0)
        atomicAdd(counter, (unsigned long long)(wsum[0] + wsum[1] + wsum[2] + wsum[3]));
}

// ---------------------------------------------------------------------------
// Pass 2: float4 streaming apply. 12,845,056 float4s = 50176 blocks x 256
// threads exactly (no bounds check). Each thread pulls 4 bits from the packed
// dilated row and writes x * scale or 0.
// ---------------------------------------------------------------------------
__global__ __launch_bounds__(256) void apply_kernel(
    const float4* __restrict__ x4,
    const uint64_t* __restrict__ dil,
    const unsigned long long* __restrict__ counter,
    float4* __restrict__ out4)
{
    const int i = blockIdx.x * 256 + threadIdx.x;   // float4 index

    // scale = countM / count_ones ; integer count is exact.
    const long long ones = COUNTM - (long long)(*counter);
    const float scale = (float)COUNTM / (float)ones;

    const int plane = i / (PLANE / 4);              // 784 float4 per plane
    const int r4    = i - plane * (PLANE / 4);
    const int h     = r4 / (Wn / 4);                // 14 float4 per row
    const int w0    = (r4 - h * (Wn / 4)) * 4;      // in {0,4,...,52}

    const uint64_t row = dil[plane * Hn + h];
    const unsigned bits = (unsigned)(row >> w0) & 0xFu;

    const float4 v = x4[i];
    float4 o;
    o.x = (bits & 1u) ? 0.0f : v.x * scale;
    o.y = (bits & 2u) ? 0.0f : v.y * scale;
    o.z = (bits & 4u) ? 0.0f : v.z * scale;
    o.w = (bits & 8u) ? 0.0f : v.w * scale;
    out4[i] = o;
}

extern "C" void kernel_launch(void* const* d_in, const int* in_sizes, int n_in,
                              void* d_out, int out_size, void* d_ws, size_t ws_size,
                              hipStream_t stream)
{
    const float* x    = (const float*)d_in[0];
    const int*   mask = (const int*)d_in[1];
    // d_in[2] = block_size (scalar 5) — fixed by the reference, hardcoded.

    unsigned long long* counter = (unsigned long long*)d_ws;
    uint64_t* dil = (uint64_t*)((char*)d_ws + 16);   // 16384*56*8 = 7,340,032 B

    // ws is re-poisoned to 0xAA before every call — zero the counter.
    hipMemsetAsync(d_ws, 0, 16, stream);

    dilate_kernel<<<NPLANES, 256, 0, stream>>>((const int4*)mask, dil);

    count_kernel<<<256, 256, 0, stream>>>(dil, counter);

    const int n4 = (int)(COUNTM / 4);                // 12,845,056 = 50176 * 256
    apply_kernel<<<n4 / 256, 256, 0, stream>>>(
        (const float4*)x, dil, counter, (float4*)d_out);
}